// Round 4
// baseline (364.013 us; speedup 1.0000x reference)
//
#include <hip/hip_runtime.h>

// SAModule (PointNet++ SA), fully fused, zero-workspace, dtype-adaptive:
// per block (4 centers, 256 thr): ball-query KNN (K=32, r=0.2) over the
// center's 4096-pt cloud -> gather feat=[x(64)|rel(3)] -> MLP 67->128->128->256
// (bf16 MFMA, fp32 acc, weights staged global->LDS per GEMM) -> masked max.
// Round-4: inputs/outputs are float32 per the reference (rounds 1-3 NaN was
// u16-misinterpretation of f32 buffers: raw pos fragments landed as NaN f32
// inside output chunk 0). A device-side probe on x's bit patterns picks the
// f32 or bf16 body, so either harness convention works.

typedef unsigned short u16;
typedef unsigned int u32;
typedef unsigned long long u64;
typedef __bf16 bf16x8 __attribute__((ext_vector_type(8)));
typedef float floatx4 __attribute__((ext_vector_type(4)));

#define PCLOUD 4096
#define DIN    64
#define MCENT  8192
#define KNBR   32
#define CAP    2048   // per-wave candidate capacity (expected in-radius ~137)

__device__ inline float bf2f(u16 u) { return __uint_as_float(((u32)u) << 16); }
__device__ inline u16 f2bf(float f) {
    u32 b = __float_as_uint(f);
    b += 0x7fffu + ((b >> 16) & 1u);   // RNE
    return (u16)(b >> 16);
}
__device__ inline u16 f2bf_s(float f) {           // never emits NaN/inf bits
    if (!(f == f)) f = 0.0f;
    f = fminf(fmaxf(f, -3.0e38f), 3.0e38f);
    return f2bf(f);
}
__device__ inline u32 pk2(float a, float b) { return (u32)f2bf_s(a) | ((u32)f2bf_s(b) << 16); }
__device__ inline u64 wave_min_u64(u64 v) {
    #pragma unroll
    for (int off = 32; off; off >>= 1) {
        u64 o = __shfl_xor((unsigned long long)v, off);
        if (o < v) v = o;
    }
    return v;
}
__device__ inline u64 d2key(float d2, int j) {
    u32 u = __float_as_uint(d2);
    u = (u & 0x80000000u) ? ~u : (u | 0x80000000u);   // order-preserving map
    return ((u64)u << 32) | (u32)j;
}

template <bool F32>
__device__ __forceinline__ float ld1(const void* p, int i) {
    if constexpr (F32) return ((const float*)p)[i];
    else               return bf2f(((const u16*)p)[i]);
}

// Stage W[k][n] (row-major f32 or bf16, row stride rs) -> sW16 B-fragment layout:
// sW16[n*128 + (((k>>3)^(n&7))<<3) + (k&7)], n=0..127 local (global n0+n),
// k=0..kslots-1 zero-filled past krows.
template <bool F32>
__device__ __forceinline__ void stage_w(const void* Wv, int rs, int n0, int krows,
                                        int kslots, u16* __restrict__ sW16, int tid) {
    int cch = tid & 15, kt = tid >> 4;
    for (int k = kt; k < kslots; k += 16) {
        u16 e[8];
        if (k < krows) {
            if constexpr (F32) {
                const float4* s4 = (const float4*)((const float*)Wv + (size_t)k * rs + n0 + cch * 8);
                float4 f0 = s4[0], f1 = s4[1];
                *(u32*)&e[0] = pk2(f0.x, f0.y); *(u32*)&e[2] = pk2(f0.z, f0.w);
                *(u32*)&e[4] = pk2(f1.x, f1.y); *(u32*)&e[6] = pk2(f1.z, f1.w);
            } else {
                *(uint4*)e = *(const uint4*)((const u16*)Wv + (size_t)k * rs + n0 + cch * 8);
            }
        } else {
            #pragma unroll
            for (int j = 0; j < 8; j++) e[j] = 0;
        }
        #pragma unroll
        for (int j = 0; j < 8; j++) {
            int n = cch * 8 + j;
            sW16[n * 128 + (((k >> 3) ^ (n & 7)) << 3) + (k & 7)] = e[j];
        }
    }
}

template <bool F32>
__device__ __forceinline__ void sa_body(
    char* __restrict__ smem, int tid, int m0,
    const void* xv, const void* posv, const int* __restrict__ batch,
    const int* __restrict__ idx,
    const void* W1v, const void* b1v, const void* W2v, const void* b2v,
    const void* W3v, const void* b3v, void* outv) {
    int w = tid >> 6, l = tid & 63;
    int m = m0 + w;
    int ic = idx[m] & (8 * PCLOUD - 1);
    float cx = ld1<F32>(posv, ic * 3 + 0), cy = ld1<F32>(posv, ic * 3 + 1),
          cz = ld1<F32>(posv, ic * 3 + 2);
    float sc = __fadd_rn(__fadd_rn(__fmul_rn(cx, cx), __fmul_rn(cy, cy)), __fmul_rn(cz, cz));
    int bcl = batch[ic] & 7;
    int base = bcl << 12;
    const float R2 = 0.04f;   // float(0.2*0.2) as jnp's weak-typed compare sees it

    if (l == 1) {
        if constexpr (F32) {
            float* out1f = (float*)outv + MCENT * 256;
            float* out2f = out1f + MCENT * 3;
            out1f[m * 3 + 0] = ((const float*)posv)[ic * 3 + 0];   // exact copies
            out1f[m * 3 + 1] = ((const float*)posv)[ic * 3 + 1];
            out1f[m * 3 + 2] = ((const float*)posv)[ic * 3 + 2];
            out2f[m] = (float)bcl;
        } else {
            u16* out1 = (u16*)outv + MCENT * 256;
            u16* out2 = out1 + MCENT * 3;
            out1[m * 3 + 0] = ((const u16*)posv)[ic * 3 + 0];
            out1[m * 3 + 1] = ((const u16*)posv)[ic * 3 + 1];
            out1[m * 3 + 2] = ((const u16*)posv)[ic * 3 + 2];
            out2[m] = f2bf((float)bcl);
        }
    }

    // ---- phase A: scan own cloud, ballot-compact in-radius keys (wave-private) ----
    u64* mylist = (u64*)smem + w * CAP;
    int c = 0;
    for (int t = l; t < PCLOUD; t += 64) {   // 64 uniform full-wave iterations
        int j = base + t;
        float px = ld1<F32>(posv, j * 3 + 0), py = ld1<F32>(posv, j * 3 + 1),
              pz = ld1<F32>(posv, j * 3 + 2);
        float sp = __fadd_rn(__fadd_rn(__fmul_rn(px, px), __fmul_rn(py, py)), __fmul_rn(pz, pz));
        float dt = __fadd_rn(__fadd_rn(__fmul_rn(cx, px), __fmul_rn(cy, py)), __fmul_rn(cz, pz));
        float d2 = __fsub_rn(__fadd_rn(sc, sp), __fmul_rn(2.0f, dt));
        bool hit = (d2 <= R2);
        u64 mk = __ballot(hit);
        if (hit) {
            int p = c + (int)__popcll(mk & ((1ull << l) - 1ull));
            if (p < CAP) mylist[p] = d2key(d2, j);
        }
        c += (int)__popcll(mk);
    }
    if (c > CAP) c = CAP;   // unreachable for uniform data (expected ~137)
    int nsel = c < KNBR ? c : KNBR;

    // ---- phase B: nsel smallest (d2,idx) keys -> register selj on lanes 0..31 ----
    int selj = -1;
    if (c <= KNBR) {
        if (l < nsel) selj = (int)(u32)(mylist[l] & 0xffffffffull);
    } else {
        u64 k0 = ~0ull, k1 = ~0ull, k2 = ~0ull, k3 = ~0ull, k4 = ~0ull, k5 = ~0ull;
        if (l < c)       k0 = mylist[l];
        if (l + 64 < c)  k1 = mylist[l + 64];
        if (l + 128 < c) k2 = mylist[l + 128];
        if (l + 192 < c) k3 = mylist[l + 192];
        if (l + 256 < c) k4 = mylist[l + 256];
        if (l + 320 < c) k5 = mylist[l + 320];
        u64 last = 0;
        for (int r = 0; r < KNBR; r++) {
            u64 mn = ~0ull;
            if (k0 > last && k0 < mn) mn = k0;
            if (k1 > last && k1 < mn) mn = k1;
            if (k2 > last && k2 < mn) mn = k2;
            if (k3 > last && k3 < mn) mn = k3;
            if (k4 > last && k4 < mn) mn = k4;
            if (k5 > last && k5 < mn) mn = k5;
            for (int s = l + 384; s < c; s += 64) {
                u64 v = mylist[s];
                if (v > last && v < mn) mn = v;
            }
            mn = wave_min_u64(mn);
            if (l == r) selj = (int)(u32)(mn & 0xffffffffull);
            last = mn;
        }
    }
    __syncthreads();   // lists dead; smem becomes sA | sW

    uint4* sA = (uint4*)smem;
    u16*  sA16 = (u16*)smem;
    uint4* sW = (uint4*)(smem + 32768);
    u16*  sW16 = (u16*)(smem + 32768);

    // ---- phase C: gather 32 feat rows (XOR 16B-chunk swizzle by row&7) + stage W1 ----
    {
        int h = l & 1, rl = l >> 1;
        int row = w * 32 + rl;
        int j = __shfl(selj, rl);
        int xv2 = row & 7;
        uint4* dst = &sA[row * 16];
        uint4 z; z.x = z.y = z.z = z.w = 0;
        int c0lo = h ? 6 : 0, c0hi = h ? 8 : 6;
        if (j >= 0) {
            for (int c0 = c0lo; c0 < c0hi; c0++) {
                uint4 pkv;
                if constexpr (F32) {
                    const float4* s4 = (const float4*)((const float*)xv + (size_t)j * DIN + c0 * 8);
                    float4 f0 = s4[0], f1 = s4[1];
                    pkv.x = pk2(f0.x, f0.y); pkv.y = pk2(f0.z, f0.w);
                    pkv.z = pk2(f1.x, f1.y); pkv.w = pk2(f1.z, f1.w);
                } else {
                    pkv = *((const uint4*)((const u16*)xv + (size_t)j * DIN) + c0);
                }
                dst[c0 ^ xv2] = pkv;
            }
            if (h == 1) {
                float rx = ld1<F32>(posv, j * 3 + 0) - cx;
                float ry = ld1<F32>(posv, j * 3 + 1) - cy;
                float rz = ld1<F32>(posv, j * 3 + 2) - cz;
                uint4 rc; rc.x = pk2(rx, ry); rc.y = (u32)f2bf_s(rz); rc.z = 0; rc.w = 0;
                dst[8 ^ xv2] = rc;
                dst[9 ^ xv2] = z; dst[10 ^ xv2] = z; dst[11 ^ xv2] = z;
            }
        } else {
            for (int c0 = c0lo; c0 < (h ? 12 : 6); c0++) dst[c0 ^ xv2] = z;
        }
        stage_w<F32>(W1v, 128, 0, 67, 96, sW16, tid);
    }
    __syncthreads();

    int m16 = l & 15, quad = l >> 4;
    int r0 = w * 32;
    const floatx4 vzero = {0.f, 0.f, 0.f, 0.f};

    // ================= GEMM1: h1 = relu(feat @ W1 + b1), K=96 =================
    {
        floatx4 acc[2][8];
        #pragma unroll
        for (int t = 0; t < 2; t++)
            #pragma unroll
            for (int cc = 0; cc < 8; cc++) acc[t][cc] = vzero;
        #pragma unroll
        for (int ki = 0; ki < 3; ki++) {
            bf16x8 a[2], b[8];
            int cb = ki * 4 + quad;
            #pragma unroll
            for (int t = 0; t < 2; t++) {
                int row = r0 + t * 16 + m16;
                a[t] = __builtin_bit_cast(bf16x8, sA[row * 16 + (cb ^ (row & 7))]);
            }
            #pragma unroll
            for (int cc = 0; cc < 8; cc++) {
                int n = cc * 16 + m16;
                b[cc] = __builtin_bit_cast(bf16x8, sW[n * 16 + (cb ^ (n & 7))]);
            }
            #pragma unroll
            for (int t = 0; t < 2; t++)
                #pragma unroll
                for (int cc = 0; cc < 8; cc++)
                    acc[t][cc] = __builtin_amdgcn_mfma_f32_16x16x32_bf16(a[t], b[cc], acc[t][cc], 0, 0, 0);
        }
        __syncthreads();
        #pragma unroll
        for (int t = 0; t < 2; t++)
            #pragma unroll
            for (int cc = 0; cc < 8; cc++) {
                int col = cc * 16 + m16;
                float bias = ld1<F32>(b1v, col);
                #pragma unroll
                for (int i = 0; i < 4; i++) {
                    int rr = r0 + t * 16 + quad * 4 + i;
                    float v = fmaxf(acc[t][cc][i] + bias, 0.0f);
                    sA16[rr * 128 + ((((col >> 3) ^ (rr & 7)) << 3) | (col & 7))] = f2bf_s(v);
                }
            }
        stage_w<F32>(W2v, 128, 0, 128, 128, sW16, tid);
    }
    __syncthreads();

    // ================= GEMM2: h2 = relu(h1 @ W2 + b2), K=128 =================
    {
        floatx4 acc[2][8];
        #pragma unroll
        for (int t = 0; t < 2; t++)
            #pragma unroll
            for (int cc = 0; cc < 8; cc++) acc[t][cc] = vzero;
        #pragma unroll
        for (int ki = 0; ki < 4; ki++) {
            bf16x8 a[2], b[8];
            int cb = ki * 4 + quad;
            #pragma unroll
            for (int t = 0; t < 2; t++) {
                int row = r0 + t * 16 + m16;
                a[t] = __builtin_bit_cast(bf16x8, sA[row * 16 + (cb ^ (row & 7))]);
            }
            #pragma unroll
            for (int cc = 0; cc < 8; cc++) {
                int n = cc * 16 + m16;
                b[cc] = __builtin_bit_cast(bf16x8, sW[n * 16 + (cb ^ (n & 7))]);
            }
            #pragma unroll
            for (int t = 0; t < 2; t++)
                #pragma unroll
                for (int cc = 0; cc < 8; cc++)
                    acc[t][cc] = __builtin_amdgcn_mfma_f32_16x16x32_bf16(a[t], b[cc], acc[t][cc], 0, 0, 0);
        }
        __syncthreads();
        #pragma unroll
        for (int t = 0; t < 2; t++)
            #pragma unroll
            for (int cc = 0; cc < 8; cc++) {
                int col = cc * 16 + m16;
                float bias = ld1<F32>(b2v, col);
                #pragma unroll
                for (int i = 0; i < 4; i++) {
                    int rr = r0 + t * 16 + quad * 4 + i;
                    float v = fmaxf(acc[t][cc][i] + bias, 0.0f);
                    sA16[rr * 128 + ((((col >> 3) ^ (rr & 7)) << 3) | (col & 7))] = f2bf_s(v);
                }
            }
        stage_w<F32>(W3v, 256, 0, 128, 128, sW16, tid);   // W3 cols 0..127
    }
    __syncthreads();

    // ====== GEMM3: h3 = relu(h2 @ W3 + b3), K=128, N=256 (two staged halves) ======
    #pragma unroll
    for (int half = 0; half < 2; half++) {
        if (half == 1) {
            __syncthreads();
            stage_w<F32>(W3v, 256, 128, 128, 128, sW16, tid);   // W3 cols 128..255
            __syncthreads();
        }
        floatx4 acc[2][8];
        #pragma unroll
        for (int t = 0; t < 2; t++)
            #pragma unroll
            for (int cc = 0; cc < 8; cc++) acc[t][cc] = vzero;
        #pragma unroll
        for (int ki = 0; ki < 4; ki++) {
            bf16x8 a[2], b[8];
            int cb = ki * 4 + quad;
            #pragma unroll
            for (int t = 0; t < 2; t++) {
                int row = r0 + t * 16 + m16;
                a[t] = __builtin_bit_cast(bf16x8, sA[row * 16 + (cb ^ (row & 7))]);
            }
            #pragma unroll
            for (int cc = 0; cc < 8; cc++) {
                int n = cc * 16 + m16;
                b[cc] = __builtin_bit_cast(bf16x8, sW[n * 16 + (cb ^ (n & 7))]);
            }
            #pragma unroll
            for (int t = 0; t < 2; t++)
                #pragma unroll
                for (int cc = 0; cc < 8; cc++)
                    acc[t][cc] = __builtin_amdgcn_mfma_f32_16x16x32_bf16(a[t], b[cc], acc[t][cc], 0, 0, 0);
        }
        #pragma unroll
        for (int cc = 0; cc < 8; cc++) {
            int col = half * 128 + cc * 16 + m16;
            float bias = ld1<F32>(b3v, col);
            float mv = 0.0f;   // post-ReLU max over >=1 valid nbr is >= 0
            #pragma unroll
            for (int t = 0; t < 2; t++)
                #pragma unroll
                for (int i = 0; i < 4; i++) {
                    int k = t * 16 + quad * 4 + i;
                    float v = fmaxf(acc[t][cc][i] + bias, 0.0f);
                    if (k < nsel) mv = fmaxf(mv, v);
                }
            mv = fmaxf(mv, __shfl_xor(mv, 16));
            mv = fmaxf(mv, __shfl_xor(mv, 32));
            if (quad == 0) {
                if constexpr (F32) ((float*)outv)[(m0 + w) * 256 + col] = mv;
                else               ((u16*)outv)[(m0 + w) * 256 + col] = f2bf_s(mv);
            }
        }
    }
}

__global__ __launch_bounds__(256, 2) void sa_kernel(
    const void* x, const void* pos, const int* __restrict__ batch,
    const int* __restrict__ idx,
    const void* W1, const void* b1, const void* W2, const void* b2,
    const void* W3, const void* b3, void* out) {
    __shared__ __align__(16) char smem[65536];
    int tid = threadIdx.x, l = tid & 63;
    // dtype probe on x's first 512 u16 words: bf16 N(0,1) values land in exp
    // [0x79,0x81] ~98% of the time; f32 bit-halves only ~51%. Uniform result.
    int cnt = 0;
    const u16* xw = (const u16*)x;
    #pragma unroll
    for (int i = 0; i < 8; i++) {
        u16 wd = xw[l * 8 + i];
        int e = (wd >> 7) & 0xFF;
        cnt += (int)__popcll(__ballot(e >= 0x79 && e <= 0x81));
    }
    int m0 = blockIdx.x * 4;
    if (cnt >= 384)
        sa_body<false>(smem, tid, m0, x, pos, batch, idx, W1, b1, W2, b2, W3, b3, out);
    else
        sa_body<true>(smem, tid, m0, x, pos, batch, idx, W1, b1, W2, b2, W3, b3, out);
}

extern "C" void kernel_launch(void* const* d_in, const int* in_sizes, int n_in,
                              void* d_out, int out_size, void* d_ws, size_t ws_size,
                              hipStream_t stream) {
    hipLaunchKernelGGL(sa_kernel, dim3(MCENT / 4), dim3(256), 0, stream,
                       d_in[0], d_in[1], (const int*)d_in[2], (const int*)d_in[3],
                       d_in[4], d_in[5], d_in[6], d_in[7], d_in[8], d_in[9],
                       d_out);
}

// Round 5
// 198.767 us; speedup vs baseline: 1.8313x; 1.8313x over previous
//
#include <hip/hip_runtime.h>

// SAModule (PointNet++ SA), fused f32-input kernel.
// Per block (4 centers, 256 thr): cooperative cloud->LDS load, ball-query KNN
// (K=32, r=0.2) with histogram top-k, gather feat=[x|rel] -> MLP 67->128->128->256
// (bf16 MFMA, fp32 acc, pre-swizzled weights from d_ws) -> masked max.
// R5: conflict-free weight staging (was 16-way scalar u16 scatter = 33% of cycles),
// LDS-resident KNN scan, histogram selection (32 wave-min rounds -> ~8).

typedef unsigned short u16;
typedef unsigned int u32;
typedef unsigned long long u64;
typedef __bf16 bf16x8 __attribute__((ext_vector_type(8)));
typedef float floatx4 __attribute__((ext_vector_type(4)));

#define PCLOUD 4096
#define DIN    64
#define MCENT  8192
#define KNBR   32
#define CAP    448

// LDS byte offsets, phase A/B (union'd with sA/sW for the GEMM phase)
#define OFF_POS   0        // float[12288]  48 KB cloud positions
#define OFF_LIST  49152    // u64[4][CAP]   14336 B candidate keys
#define OFF_HIST  63488    // u32[4][32]    d2 histogram
#define OFF_NBRL  64000    // int[4][32]    selected neighbor indices
#define OFF_CNT   64512    // int[4] acnt | int[4] cnt2

__device__ inline u16 f2bf(float f) {          // RNE, no scrub (inputs finite)
    u32 b = __float_as_uint(f);
    b += 0x7fffu + ((b >> 16) & 1u);
    return (u16)(b >> 16);
}
__device__ inline u32 pk2(float a, float b) { return (u32)f2bf(a) | ((u32)f2bf(b) << 16); }
__device__ inline u64 wave_min_u64(u64 v) {
    #pragma unroll
    for (int off = 32; off; off >>= 1) {
        u64 o = __shfl_xor((unsigned long long)v, off);
        if (o < v) v = o;
    }
    return v;
}
__device__ inline u64 d2key(float d2, int j) {
    u32 u = __float_as_uint(d2);
    u = (u & 0x80000000u) ? ~u : (u | 0x80000000u);   // order-preserving map
    return ((u64)u << 32) | (u32)j;
}
__device__ inline int key_bucket(u64 k) {
    u32 hi = (u32)(k >> 32);
    if (hi < 0x80000000u) return 0;                    // d2 <= -0
    float d2 = __uint_as_float(hi & 0x7fffffffu);
    int b = (int)(d2 * 800.0f);                        // 32 buckets over [0, 0.04]
    return b > 31 ? 31 : b;
}

// ---- prep: weights -> bf16 B-fragment images in ws (exact LDS bit layout) ----
// image g (2048 uint4): chunk[n*16 + (kc^(n&7))] = {bf16 W[kc*8+j][n0+n], j=0..7}
__global__ void prep_kernel(const float* __restrict__ W1, const float* __restrict__ W2,
                            const float* __restrict__ W3, uint4* __restrict__ ws) {
    int t = blockIdx.x * 256 + threadIdx.x;   // 0..8191
    int g = t >> 11, r = t & 2047;
    int n = r >> 4, kc = r & 15;
    const float* W; int rs, n0, krows;
    if (g == 0)      { W = W1; rs = 128; n0 = 0;   krows = 67;  }
    else if (g == 1) { W = W2; rs = 128; n0 = 0;   krows = 128; }
    else if (g == 2) { W = W3; rs = 256; n0 = 0;   krows = 128; }
    else             { W = W3; rs = 256; n0 = 128; krows = 128; }
    u16 e[8];
    #pragma unroll
    for (int j = 0; j < 8; j++) {
        int k = kc * 8 + j;
        e[j] = (k < krows) ? f2bf(W[(size_t)k * rs + n0 + n]) : (u16)0;
    }
    ws[(g << 11) + (n << 4) + (kc ^ (n & 7))] = *(const uint4*)e;
}

// Stage one 32KB weight image into sW. WS: straight copy (conflict-free b128).
// !WS fallback: per-chunk column gather + pack (still b128 writes, 8-phase optimal).
template <bool WS>
__device__ __forceinline__ void stage_img(const uint4* __restrict__ img,
                                          const float* __restrict__ W, int rs, int n0,
                                          int krows, uint4* __restrict__ sW4, int tid) {
    if constexpr (WS) {
        #pragma unroll
        for (int i = 0; i < 8; i++) sW4[i * 256 + tid] = img[i * 256 + tid];
    } else {
        int n = tid & 127, kh = (tid >> 7) * 8;
        #pragma unroll
        for (int it = 0; it < 8; it++) {
            int kc = kh + it;
            u16 e[8];
            #pragma unroll
            for (int j = 0; j < 8; j++) {
                int k = kc * 8 + j;
                e[j] = (k < krows) ? f2bf(W[(size_t)k * rs + n0 + n]) : (u16)0;
            }
            sW4[(n << 4) + (kc ^ (n & 7))] = *(const uint4*)e;
        }
    }
}

template <bool WS>
__global__ __launch_bounds__(256, 2) void sa_kernel(
    const float* __restrict__ x, const float* __restrict__ pos,
    const int* __restrict__ batch, const int* __restrict__ idx,
    const float* __restrict__ W1, const float* __restrict__ b1,
    const float* __restrict__ W2, const float* __restrict__ b2,
    const float* __restrict__ W3, const float* __restrict__ b3,
    const uint4* __restrict__ ws4, float* __restrict__ out) {
    __shared__ __align__(16) char smem[65536];
    float* posLds = (float*)(smem + OFF_POS);
    u64*  lists   = (u64*)(smem + OFF_LIST);
    u32*  hist    = (u32*)(smem + OFF_HIST);
    int*  nbrl    = (int*)(smem + OFF_NBRL);
    int*  acnt    = (int*)(smem + OFF_CNT);
    int*  cnt2    = (int*)(smem + OFF_CNT + 16);

    int tid = threadIdx.x, w = tid >> 6, l = tid & 63;
    int bid = blockIdx.x;
    int m0 = ((bid & 7) << 10) + ((bid >> 3) << 2);   // XCD-friendly: bid%8 ~ cloud
    int m = m0 + w;
    int ic = idx[m] & (8 * PCLOUD - 1);
    float cx = pos[ic * 3], cy = pos[ic * 3 + 1], cz = pos[ic * 3 + 2];
    float sc = __fadd_rn(__fadd_rn(__fmul_rn(cx, cx), __fmul_rn(cy, cy)), __fmul_rn(cz, cz));
    int bcl = batch[ic] & 7;
    int base = bcl << 12;
    const float R2 = 0.04f;

    // block-uniform cloud for the cooperative load (centers almost always share it)
    int ic0 = idx[m0] & (8 * PCLOUD - 1);
    int bcl0 = batch[ic0] & 7;
    {
        const uint4* pg = (const uint4*)pos + (size_t)bcl0 * 3072;
        uint4* pl4 = (uint4*)posLds;
        #pragma unroll
        for (int i = 0; i < 12; i++) pl4[i * 256 + tid] = pg[i * 256 + tid];
    }
    if (l < 32) hist[w * 32 + l] = 0;
    if (l == 0) { acnt[w] = 0; cnt2[w] = 0; }
    if (l == 1) {
        float* o1 = out + MCENT * 256;
        o1[m * 3] = cx; o1[m * 3 + 1] = cy; o1[m * 3 + 2] = cz;
        (o1 + MCENT * 3)[m] = (float)bcl;
    }
    __syncthreads();

    // ---- phase A: scan cloud, wave-private compaction + d2 histogram ----
    bool useLds = (bcl == bcl0);
    u64* mylist = lists + w * CAP;
    if (useLds) {
        #pragma unroll 4
        for (int t = l; t < PCLOUD; t += 64) {
            float px = posLds[t * 3], py = posLds[t * 3 + 1], pz = posLds[t * 3 + 2];
            float sp = __fadd_rn(__fadd_rn(__fmul_rn(px, px), __fmul_rn(py, py)), __fmul_rn(pz, pz));
            float dt = __fadd_rn(__fadd_rn(__fmul_rn(cx, px), __fmul_rn(cy, py)), __fmul_rn(cz, pz));
            float d2 = __fsub_rn(__fadd_rn(sc, sp), __fmul_rn(2.0f, dt));
            if (d2 <= R2) {
                int p = atomicAdd(&acnt[w], 1);
                int bkt = (int)(d2 * 800.0f);
                bkt = bkt < 0 ? 0 : (bkt > 31 ? 31 : bkt);
                atomicAdd(&hist[w * 32 + bkt], 1u);
                if (p < CAP) mylist[p] = d2key(d2, base + t);
            }
        }
    } else {
        for (int t = l; t < PCLOUD; t += 64) {
            int j = base + t;
            float px = pos[j * 3], py = pos[j * 3 + 1], pz = pos[j * 3 + 2];
            float sp = __fadd_rn(__fadd_rn(__fmul_rn(px, px), __fmul_rn(py, py)), __fmul_rn(pz, pz));
            float dt = __fadd_rn(__fadd_rn(__fmul_rn(cx, px), __fmul_rn(cy, py)), __fmul_rn(cz, pz));
            float d2 = __fsub_rn(__fadd_rn(sc, sp), __fmul_rn(2.0f, dt));
            if (d2 <= R2) {
                int p = atomicAdd(&acnt[w], 1);
                int bkt = (int)(d2 * 800.0f);
                bkt = bkt < 0 ? 0 : (bkt > 31 ? 31 : bkt);
                atomicAdd(&hist[w * 32 + bkt], 1u);
                if (p < CAP) mylist[p] = d2key(d2, j);
            }
        }
    }
    int c = acnt[w];   // same-wave LDS ops are ordered; all atomics precede this read
    int nsel = c < KNBR ? c : KNBR;

    // ---- phase B: select the 32 smallest (d2,idx) keys (set only; order free) ----
    int selj = -1;
    if (c <= KNBR) {
        if (l < c) selj = (int)(u32)mylist[l];
    } else if (c <= CAP) {
        u64 kk[7];
        #pragma unroll
        for (int i = 0; i < 7; i++) kk[i] = (l + i * 64 < c) ? mylist[l + i * 64] : ~0ull;
        int hv = (l < 32) ? (int)hist[w * 32 + l] : 0;
        #pragma unroll
        for (int off = 1; off <= 16; off <<= 1) {   // inclusive scan, lanes 0..31
            int o = __shfl_up(hv, off);
            if (l >= off) hv += o;
        }
        u64 ge = __ballot((l < 32) && (hv >= KNBR));
        int B = __ffsll((unsigned long long)ge) - 1;        // threshold bucket
        int S = (B == 0) ? 0 : __shfl(hv, B - 1);           // count strictly below B
        #pragma unroll
        for (int i = 0; i < 7; i++) {                       // bulk-select below B
            if (kk[i] != ~0ull) {
                int bkt = key_bucket(kk[i]);
                if (bkt < B) { int p = atomicAdd(&cnt2[w], 1); nbrl[w * 32 + p] = (int)(u32)kk[i]; }
                if (bkt != B) kk[i] = ~0ull;                // keep only bucket-B keys
            }
        }
        int need = KNBR - S;                                // expected ~4-12 rounds
        u64 last = 0;
        for (int r = 0; r < need; r++) {
            u64 mn = ~0ull;
            #pragma unroll
            for (int i = 0; i < 7; i++) if (kk[i] > last && kk[i] < mn) mn = kk[i];
            mn = wave_min_u64(mn);
            if (l == 0) nbrl[w * 32 + S + r] = (int)(u32)mn;
            last = mn;
        }
        if (l < KNBR) selj = nbrl[w * 32 + l];
    } else {
        // overflow fallback (never taken for uniform data): streaming 32-round argmin
        u64 last = 0;
        for (int r = 0; r < KNBR; r++) {
            u64 mn = ~0ull;
            for (int t = l; t < PCLOUD; t += 64) {
                int j = base + t;
                float px = pos[j * 3], py = pos[j * 3 + 1], pz = pos[j * 3 + 2];
                float sp = __fadd_rn(__fadd_rn(__fmul_rn(px, px), __fmul_rn(py, py)), __fmul_rn(pz, pz));
                float dt = __fadd_rn(__fadd_rn(__fmul_rn(cx, px), __fmul_rn(cy, py)), __fmul_rn(cz, pz));
                float d2 = __fsub_rn(__fadd_rn(sc, sp), __fmul_rn(2.0f, dt));
                if (d2 <= R2) { u64 kf = d2key(d2, j); if (kf > last && kf < mn) mn = kf; }
            }
            mn = wave_min_u64(mn);
            if (l == r) selj = (int)(u32)mn;
            last = mn;
        }
    }
    __syncthreads();   // lists/pos/hist dead; smem becomes sA | sW

    uint4* sA4 = (uint4*)smem;
    u16*  sA16 = (u16*)smem;
    uint4* sW4 = (uint4*)(smem + 32768);

    // ---- gather 32 feat rows per wave (XOR 16B-chunk swizzle) + stage W1 ----
    {
        int h = l & 1, rl = l >> 1;
        int row = w * 32 + rl;
        int j = __shfl(selj, rl);
        int xv = row & 7;
        uint4* dst = sA4 + row * 16;
        uint4 z; z.x = z.y = z.z = z.w = 0;
        if (j >= 0) {
            const float4* sx = (const float4*)(x + (size_t)j * DIN);
            int c0lo = h ? 6 : 0, c0hi = h ? 8 : 6;
            for (int c0 = c0lo; c0 < c0hi; c0++) {
                float4 f0 = sx[c0 * 2], f1 = sx[c0 * 2 + 1];
                uint4 pv;
                pv.x = pk2(f0.x, f0.y); pv.y = pk2(f0.z, f0.w);
                pv.z = pk2(f1.x, f1.y); pv.w = pk2(f1.z, f1.w);
                dst[c0 ^ xv] = pv;
            }
            if (h == 1) {
                float rx = pos[j * 3] - cx, ry = pos[j * 3 + 1] - cy, rz = pos[j * 3 + 2] - cz;
                uint4 rc; rc.x = pk2(rx, ry); rc.y = (u32)f2bf(rz); rc.z = 0; rc.w = 0;
                dst[8 ^ xv] = rc;
                dst[9 ^ xv] = z; dst[10 ^ xv] = z; dst[11 ^ xv] = z;
            }
        } else {
            int c0lo = h ? 6 : 0, c0hi = h ? 12 : 6;
            for (int c0 = c0lo; c0 < c0hi; c0++) dst[c0 ^ xv] = z;
        }
        stage_img<WS>(ws4, W1, 128, 0, 67, sW4, tid);
    }
    __syncthreads();

    int m16 = l & 15, quad = l >> 4;
    int r0 = w * 32;
    const floatx4 vzero = {0.f, 0.f, 0.f, 0.f};

    // ================= GEMM1: h1 = relu(feat @ W1 + b1), K=96 =================
    {
        floatx4 acc[2][8];
        #pragma unroll
        for (int t = 0; t < 2; t++)
            #pragma unroll
            for (int cc = 0; cc < 8; cc++) acc[t][cc] = vzero;
        #pragma unroll
        for (int ki = 0; ki < 3; ki++) {
            bf16x8 a[2], b[8];
            int cb = ki * 4 + quad;
            #pragma unroll
            for (int t = 0; t < 2; t++) {
                int row = r0 + t * 16 + m16;
                a[t] = __builtin_bit_cast(bf16x8, sA4[row * 16 + (cb ^ (row & 7))]);
            }
            #pragma unroll
            for (int cc = 0; cc < 8; cc++) {
                int n = cc * 16 + m16;
                b[cc] = __builtin_bit_cast(bf16x8, sW4[n * 16 + (cb ^ (n & 7))]);
            }
            #pragma unroll
            for (int t = 0; t < 2; t++)
                #pragma unroll
                for (int cc = 0; cc < 8; cc++)
                    acc[t][cc] = __builtin_amdgcn_mfma_f32_16x16x32_bf16(a[t], b[cc], acc[t][cc], 0, 0, 0);
        }
        __syncthreads();
        #pragma unroll
        for (int t = 0; t < 2; t++)
            #pragma unroll
            for (int cc = 0; cc < 8; cc++) {
                int col = cc * 16 + m16;
                float bias = b1[col];
                #pragma unroll
                for (int i = 0; i < 4; i++) {
                    int rr = r0 + t * 16 + quad * 4 + i;
                    float v = fmaxf(acc[t][cc][i] + bias, 0.0f);
                    sA16[rr * 128 + ((((col >> 3) ^ (rr & 7)) << 3) | (col & 7))] = f2bf(v);
                }
            }
        stage_img<WS>(ws4 + 2048, W2, 128, 0, 128, sW4, tid);
    }
    __syncthreads();

    // ================= GEMM2: h2 = relu(h1 @ W2 + b2), K=128 =================
    {
        floatx4 acc[2][8];
        #pragma unroll
        for (int t = 0; t < 2; t++)
            #pragma unroll
            for (int cc = 0; cc < 8; cc++) acc[t][cc] = vzero;
        #pragma unroll
        for (int ki = 0; ki < 4; ki++) {
            bf16x8 a[2], b[8];
            int cb = ki * 4 + quad;
            #pragma unroll
            for (int t = 0; t < 2; t++) {
                int row = r0 + t * 16 + m16;
                a[t] = __builtin_bit_cast(bf16x8, sA4[row * 16 + (cb ^ (row & 7))]);
            }
            #pragma unroll
            for (int cc = 0; cc < 8; cc++) {
                int n = cc * 16 + m16;
                b[cc] = __builtin_bit_cast(bf16x8, sW4[n * 16 + (cb ^ (n & 7))]);
            }
            #pragma unroll
            for (int t = 0; t < 2; t++)
                #pragma unroll
                for (int cc = 0; cc < 8; cc++)
                    acc[t][cc] = __builtin_amdgcn_mfma_f32_16x16x32_bf16(a[t], b[cc], acc[t][cc], 0, 0, 0);
        }
        __syncthreads();
        #pragma unroll
        for (int t = 0; t < 2; t++)
            #pragma unroll
            for (int cc = 0; cc < 8; cc++) {
                int col = cc * 16 + m16;
                float bias = b2[col];
                #pragma unroll
                for (int i = 0; i < 4; i++) {
                    int rr = r0 + t * 16 + quad * 4 + i;
                    float v = fmaxf(acc[t][cc][i] + bias, 0.0f);
                    sA16[rr * 128 + ((((col >> 3) ^ (rr & 7)) << 3) | (col & 7))] = f2bf(v);
                }
            }
        stage_img<WS>(ws4 + 4096, W3, 256, 0, 128, sW4, tid);   // W3 cols 0..127
    }
    __syncthreads();

    // ====== GEMM3: h3 = relu(h2 @ W3 + b3), K=128, N=256 (two staged halves) ======
    #pragma unroll
    for (int half = 0; half < 2; half++) {
        if (half == 1) {
            __syncthreads();
            stage_img<WS>(ws4 + 6144, W3, 256, 128, 128, sW4, tid);   // cols 128..255
            __syncthreads();
        }
        floatx4 acc[2][8];
        #pragma unroll
        for (int t = 0; t < 2; t++)
            #pragma unroll
            for (int cc = 0; cc < 8; cc++) acc[t][cc] = vzero;
        #pragma unroll
        for (int ki = 0; ki < 4; ki++) {
            bf16x8 a[2], b[8];
            int cb = ki * 4 + quad;
            #pragma unroll
            for (int t = 0; t < 2; t++) {
                int row = r0 + t * 16 + m16;
                a[t] = __builtin_bit_cast(bf16x8, sA4[row * 16 + (cb ^ (row & 7))]);
            }
            #pragma unroll
            for (int cc = 0; cc < 8; cc++) {
                int n = cc * 16 + m16;
                b[cc] = __builtin_bit_cast(bf16x8, sW4[n * 16 + (cb ^ (n & 7))]);
            }
            #pragma unroll
            for (int t = 0; t < 2; t++)
                #pragma unroll
                for (int cc = 0; cc < 8; cc++)
                    acc[t][cc] = __builtin_amdgcn_mfma_f32_16x16x32_bf16(a[t], b[cc], acc[t][cc], 0, 0, 0);
        }
        #pragma unroll
        for (int cc = 0; cc < 8; cc++) {
            int col = half * 128 + cc * 16 + m16;
            float bias = b3[col];
            float mv = 0.0f;   // post-ReLU max over >=1 valid nbr is >= 0
            #pragma unroll
            for (int t = 0; t < 2; t++)
                #pragma unroll
                for (int i = 0; i < 4; i++) {
                    int k = t * 16 + quad * 4 + i;
                    float v = fmaxf(acc[t][cc][i] + bias, 0.0f);
                    if (k < nsel) mv = fmaxf(mv, v);
                }
            mv = fmaxf(mv, __shfl_xor(mv, 16));
            mv = fmaxf(mv, __shfl_xor(mv, 32));
            if (quad == 0) out[(m0 + w) * 256 + col] = mv;
        }
    }
}

extern "C" void kernel_launch(void* const* d_in, const int* in_sizes, int n_in,
                              void* d_out, int out_size, void* d_ws, size_t ws_size,
                              hipStream_t stream) {
    const float* x     = (const float*)d_in[0];
    const float* pos   = (const float*)d_in[1];
    const int*   batch = (const int*)d_in[2];
    const int*   idx   = (const int*)d_in[3];
    const float* W1    = (const float*)d_in[4];
    const float* b1    = (const float*)d_in[5];
    const float* W2    = (const float*)d_in[6];
    const float* b2    = (const float*)d_in[7];
    const float* W3    = (const float*)d_in[8];
    const float* b3    = (const float*)d_in[9];
    float* out = (float*)d_out;
    uint4* ws4 = (uint4*)d_ws;

    if (ws_size >= 131072) {
        hipLaunchKernelGGL(prep_kernel, dim3(32), dim3(256), 0, stream, W1, W2, W3, ws4);
        hipLaunchKernelGGL((sa_kernel<true>), dim3(MCENT / 4), dim3(256), 0, stream,
                           x, pos, batch, idx, W1, b1, W2, b2, W3, b3, ws4, out);
    } else {
        hipLaunchKernelGGL((sa_kernel<false>), dim3(MCENT / 4), dim3(256), 0, stream,
                           x, pos, batch, idx, W1, b1, W2, b2, W3, b3, ws4, out);
    }
}